// Round 4
// baseline (5064.376 us; speedup 1.0000x reference)
//
#include <hip/hip_runtime.h>
#include <stdint.h>

#define TT 2560
#define BB 64
#define CC 22
#define CP 24

typedef unsigned short ushort_t;
typedef __attribute__((ext_vector_type(4))) float floatx4;
typedef __attribute__((ext_vector_type(8))) short bf16x8;

__device__ __forceinline__ float bf2f(ushort_t u){
  union { uint32_t i; float f; } v; v.i = ((uint32_t)u) << 16; return v.f;
}
__device__ __forceinline__ ushort_t f2bf(float f){
  union { float f; uint32_t i; } v; v.f = f;
  uint32_t r = v.i + 0x7FFFu + ((v.i >> 16) & 1u);
  return (ushort_t)(r >> 16);
}
__device__ __forceinline__ float fsig(float x){ return 1.f/(1.f + __expf(-x)); }
__device__ __forceinline__ float ftanh(float x){ return 2.f/(1.f + __expf(-2.f*x)) - 1.f; }

// LDS-only barrier: does NOT drain vmcnt, so global stores and prefetch loads
// stay in flight across the 2560-step serial loop.
__device__ __forceinline__ void ldsbar(){
  asm volatile("s_waitcnt lgkmcnt(0)\n\ts_barrier" ::: "memory");
}

// ---------------- K0a: transpose x [B][C][T] -> xT [B][T][CP] bf16 (pad c=22,23 with 0)
__global__ __launch_bounds__(256) void k_transpose_x(const float* __restrict__ x, ushort_t* __restrict__ xT){
  int idx = blockIdx.x*256 + threadIdx.x;
  if (idx >= BB*TT) return;
  int b = idx / TT, t = idx % TT;
  ushort_t* dst = xT + (size_t)idx*CP;
  const float* src = x + (size_t)b*CC*TT + t;
  #pragma unroll
  for (int c=0;c<CC;c++) dst[c] = f2bf(src[(size_t)c*TT]);
  dst[22] = 0; dst[23] = 0;
}

// ---------------- K0b: B0T[dir][n=512][k=160]: k<128 -> Wh0[k][n]; 128<=k<150 -> Wx0[k-128][n]; else 0
__global__ __launch_bounds__(256) void k_prep_l0(const float* __restrict__ WxF, const float* __restrict__ WhF,
                                                 const float* __restrict__ WxB, const float* __restrict__ WhB,
                                                 ushort_t* __restrict__ B0T){
  int idx = blockIdx.x*256 + threadIdx.x;
  if (idx >= 2*512*160) return;
  int dir = idx / 81920; int r = idx % 81920; int n = r / 160; int k = r % 160;
  const float* Wh = dir ? WhB : WhF;
  const float* Wx = dir ? WxB : WxF;
  float v = (k < 128) ? Wh[k*512 + n] : (((k-128) < CC) ? Wx[(k-128)*512 + n] : 0.f);
  B0T[idx] = f2bf(v);
}

// ---------------- K0c: B1T[dir][n=256][k=64] = Wh1[k][n]
__global__ __launch_bounds__(256) void k_prep_l1(const float* __restrict__ WhF, const float* __restrict__ WhB,
                                                 ushort_t* __restrict__ B1T){
  int idx = blockIdx.x*256 + threadIdx.x;
  if (idx >= 2*256*64) return;
  int dir = idx >> 14; int r = idx & 16383; int n = r >> 6; int k = r & 63;
  const float* Wh = dir ? WhB : WhF;
  B1T[idx] = f2bf(Wh[k*256 + n]);
}

// ---------------- K0d: WT[dir][n=256][k=256] = Wx1[k][n]  (for xz1 gemm)
__global__ __launch_bounds__(256) void k_prep_wxT(const float* __restrict__ Wf, const float* __restrict__ Wb,
                                                  ushort_t* __restrict__ WT){
  int idx = blockIdx.x*256 + threadIdx.x;
  int dir = idx >> 16; int r = idx & 65535; int n = r >> 8; int k = r & 255;
  const float* W = dir ? Wb : Wf;
  WT[idx] = f2bf(W[k*256 + n]);
}

// ---------------- K1: layer-0 MFMA scan, 2 interleaved chain-groups of 4 per WG (16 WGs).
// Group g chains sit at C-rows {0,4,8,12}; lane q owns chain q of each group.
// Weight B-fragments (80 VGPR) are shared across groups (same dir).
__global__ __launch_bounds__(512, 1) void k_lstm0m(
  const ushort_t* __restrict__ xT, const ushort_t* __restrict__ B0T,
  const float* __restrict__ bF, const float* __restrict__ bB,
  ushort_t* __restrict__ h0seq)                     // [B][T][256]: fwd 0..127, bwd 128..255
{
  const int dir = blockIdx.x & 1, cb2 = blockIdx.x >> 1;  // cb2 0..7, 8 chains/WG
  const int tid = threadIdx.x;
  const int wv = tid >> 6, lane = tid & 63, m = lane & 15, q = lane >> 4;
  const int u = wv*16 + m;                                // unit 0..127
  const float* bi = dir ? bB : bF;

  __shared__ __align__(16) ushort_t Abuf[2][2][16][168]; // [group][buf][row][h0..127|x128..151|0]

  bf16x8 Bf[4][5];
  const ushort_t* Bb = B0T + (size_t)dir*512*160;
  #pragma unroll
  for (int g=0; g<4; g++){
    int ntile = wv + g*8;
    #pragma unroll
    for (int kt=0; kt<5; kt++)
      Bf[g][kt] = *(const bf16x8*)(Bb + (size_t)(ntile*16+m)*160 + kt*32 + q*8);
  }
  const float b0 = bi[u], b1 = bi[128+u], b2 = bi[256+u], b3 = bi[384+u];

  for (int i = tid; i < (int)(sizeof(Abuf)/4); i += 512) ((uint32_t*)Abuf)[i] = 0u;
  __syncthreads();

  // x staging: tid<192 covers 2 groups x 4 chains x 24 channels
  int gs=0, chain=0, cx=0; const ushort_t* xrow = nullptr;
  ushort_t xreg = 0, xreg2 = 0;
  if (tid < 192){
    gs = tid / 96; int r = tid % 96; chain = r / 24; cx = r - chain*24;
    xrow = xT + ((size_t)((cb2*2 + gs)*4 + chain)*TT)*CP + cx;
    int t0 = dir ? TT-1 : 0;
    int t1 = dir ? TT-2 : 1;
    int t2 = dir ? TT-3 : 2;
    Abuf[gs][0][chain*4][128+cx] = xrow[(size_t)t0*CP];
    xreg  = xrow[(size_t)t1*CP];
    xreg2 = xrow[(size_t)t2*CP];
  }
  __syncthreads();

  float cst0 = 0.f, cst1 = 0.f;
  const int t00 = dir ? TT-1 : 0;
  ushort_t* hp0 = h0seq + ((size_t)(cb2*8 + 0*4 + q)*TT + t00)*256 + dir*128 + u;
  ushort_t* hp1 = h0seq + ((size_t)(cb2*8 + 1*4 + q)*TT + t00)*256 + dir*128 + u;
  const int hstep = dir ? -256 : 256;

  for (int s = 0; s < TT; ++s){
    const int cur = s & 1, nxt = cur ^ 1;

    bf16x8 Af0[5], Af1[5];
    const ushort_t* a0p = &Abuf[0][cur][m][0];
    const ushort_t* a1p = &Abuf[1][cur][m][0];
    #pragma unroll
    for (int kt=0; kt<5; kt++) Af0[kt] = *(const bf16x8*)(a0p + kt*32 + q*8);
    #pragma unroll
    for (int kt=0; kt<5; kt++) Af1[kt] = *(const bf16x8*)(a1p + kt*32 + q*8);

    floatx4 g0a0 = {b0,b0,b0,b0}, g0a1 = {b1,b1,b1,b1}, g0a2 = {b2,b2,b2,b2}, g0a3 = {b3,b3,b3,b3};
    floatx4 g1a0 = {b0,b0,b0,b0}, g1a1 = {b1,b1,b1,b1}, g1a2 = {b2,b2,b2,b2}, g1a3 = {b3,b3,b3,b3};
    #pragma unroll
    for (int kt=0; kt<5; kt++){
      g0a0 = __builtin_amdgcn_mfma_f32_16x16x32_bf16(Af0[kt], Bf[0][kt], g0a0, 0,0,0);
      g0a1 = __builtin_amdgcn_mfma_f32_16x16x32_bf16(Af0[kt], Bf[1][kt], g0a1, 0,0,0);
      g0a2 = __builtin_amdgcn_mfma_f32_16x16x32_bf16(Af0[kt], Bf[2][kt], g0a2, 0,0,0);
      g0a3 = __builtin_amdgcn_mfma_f32_16x16x32_bf16(Af0[kt], Bf[3][kt], g0a3, 0,0,0);
    }
    #pragma unroll
    for (int kt=0; kt<5; kt++){
      g1a0 = __builtin_amdgcn_mfma_f32_16x16x32_bf16(Af1[kt], Bf[0][kt], g1a0, 0,0,0);
      g1a1 = __builtin_amdgcn_mfma_f32_16x16x32_bf16(Af1[kt], Bf[1][kt], g1a1, 0,0,0);
      g1a2 = __builtin_amdgcn_mfma_f32_16x16x32_bf16(Af1[kt], Bf[2][kt], g1a2, 0,0,0);
      g1a3 = __builtin_amdgcn_mfma_f32_16x16x32_bf16(Af1[kt], Bf[3][kt], g1a3, 0,0,0);
    }

    ushort_t xnew = 0;
    if (tid < 192){                       // depth-2 x prefetch, never drained at barrier
      int sn = s + 3; if (sn > TT-1) sn = TT-1;
      int tn = dir ? (TT-1-sn) : sn;
      xnew = xrow[(size_t)tn*CP];
    }

    {  // group 0 gates (chain q)
      float ig = fsig(g0a0[0]);
      float fg = fsig(g0a1[0]);
      float gg = ftanh(g0a2[0]);
      float og = fsig(g0a3[0]);
      float cc = fg*cst0 + ig*gg;
      cst0 = cc;
      ushort_t hv = f2bf(og*ftanh(cc));
      Abuf[0][nxt][q*4][u] = hv;
      *hp0 = hv; hp0 += hstep;
    }
    {  // group 1 gates
      float ig = fsig(g1a0[0]);
      float fg = fsig(g1a1[0]);
      float gg = ftanh(g1a2[0]);
      float og = fsig(g1a3[0]);
      float cc = fg*cst1 + ig*gg;
      cst1 = cc;
      ushort_t hv = f2bf(og*ftanh(cc));
      Abuf[1][nxt][q*4][u] = hv;
      *hp1 = hv; hp1 += hstep;
    }
    if (tid < 192){
      Abuf[gs][nxt][chain*4][128+cx] = xreg;
      xreg = xreg2; xreg2 = xnew;
    }
    ldsbar();
  }
}

// ---------------- K2: xz1[dir][bt][256] = bf16( h0seq[bt][:256] @ Wx1[dir] )
__global__ __launch_bounds__(512) void k_xz1_gemm(const ushort_t* __restrict__ h0seq,
                                                  const ushort_t* __restrict__ WxT,
                                                  ushort_t* __restrict__ xz1)
{
  const int mb  = blockIdx.x;
  const int dir = blockIdx.y;
  const ushort_t* W   = WxT + (size_t)dir*256*256;
  ushort_t*       out = xz1 + (size_t)dir*BB*TT*256;
  const int wave = threadIdx.x >> 6;
  const int lane = threadIdx.x & 63;
  const int mw = wave & 3;
  const int nw = wave >> 2;
  const int m_ = lane & 15;
  const int q_ = lane >> 4;

  floatx4 acc[2][8];
  #pragma unroll
  for (int a=0;a<2;a++)
    #pragma unroll
    for (int n=0;n<8;n++) acc[a][n] = (floatx4)0.f;

  const size_t Abase = ((size_t)mb*128 + mw*32 + m_)*256 + q_*8;
  const size_t Bbase = ((size_t)nw*128 + m_)*256 + q_*8;

  for (int kc = 0; kc < 256; kc += 32){
    bf16x8 afr[2];
    #pragma unroll
    for (int mt=0;mt<2;mt++)
      afr[mt] = *(const bf16x8*)(h0seq + Abase + (size_t)mt*16*256 + kc);
    #pragma unroll
    for (int nt=0;nt<8;nt++){
      bf16x8 bfr = *(const bf16x8*)(W + Bbase + (size_t)nt*16*256 + kc);
      #pragma unroll
      for (int mt=0;mt<2;mt++)
        acc[mt][nt] = __builtin_amdgcn_mfma_f32_16x16x32_bf16(afr[mt], bfr, acc[mt][nt], 0,0,0);
    }
  }
  #pragma unroll
  for (int mt=0;mt<2;mt++)
    #pragma unroll
    for (int nt=0;nt<8;nt++)
      #pragma unroll
      for (int r=0;r<4;r++){
        size_t row = (size_t)mb*128 + mw*32 + mt*16 + q_*4 + r;
        int    col = nw*128 + nt*16 + m_;
        out[row*256 + col] = f2bf(acc[mt][nt][r]);
      }
}

// ---------------- K3: layer-1 MFMA scan, 2 interleaved groups of 4 chains per WG (16 WGs, 4 waves).
__global__ __launch_bounds__(256, 1) void k_lstm1m(
  const ushort_t* __restrict__ xz1,                 // [dir][b*T+t][256] bf16
  const ushort_t* __restrict__ B1T,                 // [dir][n=256][k=64] bf16
  const float* __restrict__ bF, const float* __restrict__ bB,
  float* __restrict__ h1last)                       // [B][128]: fwd 0..63, bwd 64..127
{
  const int dir = blockIdx.x & 1, cb2 = blockIdx.x >> 1;  // cb2 0..7
  const int tid = threadIdx.x;
  const int wv = tid >> 6, lane = tid & 63, m = lane & 15, q = lane >> 4;
  const int u = wv*16 + m;                                // unit 0..63
  const float* bi = dir ? bB : bF;

  __shared__ __align__(16) ushort_t Hbuf[2][2][16][88];
  __shared__ __align__(16) ushort_t XZbuf[2][2][4][264];

  bf16x8 Bf[4][2];                        // shared across groups (same dir)
  const ushort_t* Bb = B1T + (size_t)dir*256*64;
  #pragma unroll
  for (int g=0; g<4; g++){
    int ntile = wv + g*4;
    #pragma unroll
    for (int kt=0; kt<2; kt++)
      Bf[g][kt] = *(const bf16x8*)(Bb + (size_t)(ntile*16+m)*64 + kt*32 + q*8);
  }
  const float b0 = bi[u], b1 = bi[64+u], b2 = bi[128+u], b3 = bi[192+u];

  for (int i = tid; i < (int)(sizeof(Hbuf)/4); i += 256) ((uint32_t*)Hbuf)[i] = 0u;

  // xz staging: 8 chains x 32 lanes x 16B = 4KB/step
  const int ch8 = tid >> 5;               // 0..7: group = ch8>>2, chain = ch8&3
  const int l2  = tid & 31;
  const int gsc = ch8 >> 2, cc_ = ch8 & 3;
  const ushort_t* xzr = xz1 + (size_t)dir*BB*TT*256 + ((size_t)(cb2*8 + ch8)*TT)*256 + l2*8;
  uint4 pA, pB;
  {
    int t0 = dir ? TT-1 : 0;
    int t1 = dir ? TT-2 : 1;
    int t2 = dir ? TT-3 : 2;
    *(uint4*)&XZbuf[gsc][0][cc_][l2*8] = *(const uint4*)(xzr + (size_t)t0*256);
    pA = *(const uint4*)(xzr + (size_t)t1*256);
    pB = *(const uint4*)(xzr + (size_t)t2*256);
  }
  __syncthreads();

  float cst0 = 0.f, cst1 = 0.f, hl0 = 0.f, hl1 = 0.f;

  for (int s = 0; s < TT; ++s){
    const int cur = s & 1, nxt = cur ^ 1;

    bf16x8 Af0[2], Af1[2];
    const ushort_t* a0p = &Hbuf[0][cur][m][0];
    const ushort_t* a1p = &Hbuf[1][cur][m][0];
    Af0[0] = *(const bf16x8*)(a0p + q*8);
    Af0[1] = *(const bf16x8*)(a0p + 32 + q*8);
    Af1[0] = *(const bf16x8*)(a1p + q*8);
    Af1[1] = *(const bf16x8*)(a1p + 32 + q*8);

    floatx4 g0a0 = {b0,b0,b0,b0}, g0a1 = {b1,b1,b1,b1}, g0a2 = {b2,b2,b2,b2}, g0a3 = {b3,b3,b3,b3};
    floatx4 g1a0 = {b0,b0,b0,b0}, g1a1 = {b1,b1,b1,b1}, g1a2 = {b2,b2,b2,b2}, g1a3 = {b3,b3,b3,b3};
    #pragma unroll
    for (int kt=0; kt<2; kt++){
      g0a0 = __builtin_amdgcn_mfma_f32_16x16x32_bf16(Af0[kt], Bf[0][kt], g0a0, 0,0,0);
      g0a1 = __builtin_amdgcn_mfma_f32_16x16x32_bf16(Af0[kt], Bf[1][kt], g0a1, 0,0,0);
      g0a2 = __builtin_amdgcn_mfma_f32_16x16x32_bf16(Af0[kt], Bf[2][kt], g0a2, 0,0,0);
      g0a3 = __builtin_amdgcn_mfma_f32_16x16x32_bf16(Af0[kt], Bf[3][kt], g0a3, 0,0,0);
    }
    #pragma unroll
    for (int kt=0; kt<2; kt++){
      g1a0 = __builtin_amdgcn_mfma_f32_16x16x32_bf16(Af1[kt], Bf[0][kt], g1a0, 0,0,0);
      g1a1 = __builtin_amdgcn_mfma_f32_16x16x32_bf16(Af1[kt], Bf[1][kt], g1a1, 0,0,0);
      g1a2 = __builtin_amdgcn_mfma_f32_16x16x32_bf16(Af1[kt], Bf[2][kt], g1a2, 0,0,0);
      g1a3 = __builtin_amdgcn_mfma_f32_16x16x32_bf16(Af1[kt], Bf[3][kt], g1a3, 0,0,0);
    }

    // publish xz(s+1) into nxt; issue load for s+3 (2-step slack, in flight over ldsbar)
    *(uint4*)&XZbuf[gsc][nxt][cc_][l2*8] = pA;
    pA = pB;
    {
      int sn = s + 3; if (sn > TT-1) sn = TT-1;
      int tn = dir ? (TT-1-sn) : sn;
      pB = *(const uint4*)(xzr + (size_t)tn*256);
    }

    {  // group 0 gates
      float zi = g0a0[0] + bf2f(XZbuf[0][cur][q][u]);
      float zf = g0a1[0] + bf2f(XZbuf[0][cur][q][64 + u]);
      float zg = g0a2[0] + bf2f(XZbuf[0][cur][q][128 + u]);
      float zo = g0a3[0] + bf2f(XZbuf[0][cur][q][192 + u]);
      float ig = fsig(zi), fg = fsig(zf), og = fsig(zo);
      float gg = ftanh(zg);
      float cc2 = fg*cst0 + ig*gg;
      cst0 = cc2;
      hl0 = og*ftanh(cc2);
      Hbuf[0][nxt][q*4][u] = f2bf(hl0);
    }
    {  // group 1 gates
      float zi = g1a0[0] + bf2f(XZbuf[1][cur][q][u]);
      float zf = g1a1[0] + bf2f(XZbuf[1][cur][q][64 + u]);
      float zg = g1a2[0] + bf2f(XZbuf[1][cur][q][128 + u]);
      float zo = g1a3[0] + bf2f(XZbuf[1][cur][q][192 + u]);
      float ig = fsig(zi), fg = fsig(zf), og = fsig(zo);
      float gg = ftanh(zg);
      float cc2 = fg*cst1 + ig*gg;
      cst1 = cc2;
      hl1 = og*ftanh(cc2);
      Hbuf[1][nxt][q*4][u] = f2bf(hl1);
    }
    ldsbar();
  }
  h1last[(size_t)(cb2*8 + 0*4 + q)*128 + dir*64 + u] = hl0;
  h1last[(size_t)(cb2*8 + 1*4 + q)*128 + dir*64 + u] = hl1;
}

// ---------------- K4: dense head
__global__ __launch_bounds__(128) void k_head(
  const float* __restrict__ h1last,
  const float* __restrict__ d0W, const float* __restrict__ d0b,
  const float* __restrict__ d1W, const float* __restrict__ d1b,
  const float* __restrict__ oW,  const float* __restrict__ ob,
  float* __restrict__ outp)
{
  const int b = blockIdx.x;
  const int j = threadIdx.x;
  __shared__ float v0[128], v1[128];
  v0[j] = h1last[b*128 + j];
  __syncthreads();
  float acc = d0b[j];
  #pragma unroll
  for (int k=0;k<128;k++) acc += v0[k]*d0W[k*128 + j];
  v1[j] = fmaxf(acc, 0.f);
  __syncthreads();
  if (j < 64){
    float a2 = d1b[j];
    #pragma unroll
    for (int k=0;k<128;k++) a2 += v1[k]*d1W[k*64 + j];
    float p = fmaxf(a2, 0.f) * oW[j];
    #pragma unroll
    for (int off=32; off>0; off>>=1) p += __shfl_down(p, off, 64);
    if (j == 0) outp[b] = 1.f/(1.f + __expf(-(p + ob[0])));
  }
}

extern "C" void kernel_launch(void* const* d_in, const int* in_sizes, int n_in,
                              void* d_out, int out_size, void* d_ws, size_t ws_size,
                              hipStream_t stream)
{
  const float* x     = (const float*)d_in[0];
  const float* l0fWx = (const float*)d_in[1];
  const float* l0fWh = (const float*)d_in[2];
  const float* l0fb  = (const float*)d_in[3];
  const float* l0bWx = (const float*)d_in[4];
  const float* l0bWh = (const float*)d_in[5];
  const float* l0bb  = (const float*)d_in[6];
  const float* l1fWx = (const float*)d_in[7];
  const float* l1fWh = (const float*)d_in[8];
  const float* l1fb  = (const float*)d_in[9];
  const float* l1bWx = (const float*)d_in[10];
  const float* l1bWh = (const float*)d_in[11];
  const float* l1bb  = (const float*)d_in[12];
  const float* d0W = (const float*)d_in[13];
  const float* d0b = (const float*)d_in[14];
  const float* d1W = (const float*)d_in[15];
  const float* d1b = (const float*)d_in[16];
  const float* oW  = (const float*)d_in[17];
  const float* ob  = (const float*)d_in[18];
  float* outp = (float*)d_out;

  char* ws = (char*)d_ws;
  const size_t OFF_XT  = 0;                        // 7,864,320
  const size_t OFF_H0  = OFF_XT  + 7864320ull;     // 83,886,080
  const size_t OFF_XZ  = OFF_H0  + 83886080ull;    // 167,772,160
  const size_t OFF_WT  = OFF_XZ  + 167772160ull;   // 262,144
  const size_t OFF_B0  = OFF_WT  + 262144ull;      // 327,680
  const size_t OFF_B1  = OFF_B0  + 327680ull;      // 65,536
  const size_t OFF_H1  = OFF_B1  + 65536ull;       // 32,768

  ushort_t* xT  = (ushort_t*)(ws + OFF_XT);
  ushort_t* h0  = (ushort_t*)(ws + OFF_H0);
  ushort_t* xz1 = (ushort_t*)(ws + OFF_XZ);
  ushort_t* WT  = (ushort_t*)(ws + OFF_WT);
  ushort_t* B0T = (ushort_t*)(ws + OFF_B0);
  ushort_t* B1T = (ushort_t*)(ws + OFF_B1);
  float*    h1l = (float*)(ws + OFF_H1);

  hipLaunchKernelGGL(k_transpose_x, dim3(640), dim3(256), 0, stream, x, xT);
  hipLaunchKernelGGL(k_prep_l0,     dim3(640), dim3(256), 0, stream, l0fWx, l0fWh, l0bWx, l0bWh, B0T);
  hipLaunchKernelGGL(k_prep_l1,     dim3(128), dim3(256), 0, stream, l1fWh, l1bWh, B1T);
  hipLaunchKernelGGL(k_prep_wxT,    dim3(512), dim3(256), 0, stream, l1fWx, l1bWx, WT);
  hipLaunchKernelGGL(k_lstm0m,      dim3(16),  dim3(512), 0, stream, xT, B0T, l0fb, l0bb, h0);
  hipLaunchKernelGGL(k_xz1_gemm,    dim3(1280,2), dim3(512), 0, stream, h0, WT, xz1);
  hipLaunchKernelGGL(k_lstm1m,      dim3(16),  dim3(256), 0, stream, xz1, B1T, l1fb, l1bb, h1l);
  hipLaunchKernelGGL(k_head,        dim3(64),  dim3(128), 0, stream,
                     h1l, d0W, d0b, d1W, d1b, oW, ob, outp);
}

// Round 5
// 3264.025 us; speedup vs baseline: 1.5516x; 1.5516x over previous
//
#include <hip/hip_runtime.h>
#include <stdint.h>

#define TT 2560
#define BB 64
#define CC 22
#define CP 24

typedef unsigned short ushort_t;
typedef __attribute__((ext_vector_type(4))) float floatx4;
typedef __attribute__((ext_vector_type(8))) short bf16x8;

__device__ __forceinline__ float bf2f(ushort_t u){
  union { uint32_t i; float f; } v; v.i = ((uint32_t)u) << 16; return v.f;
}
__device__ __forceinline__ ushort_t f2bf(float f){
  union { float f; uint32_t i; } v; v.f = f;
  uint32_t r = v.i + 0x7FFFu + ((v.i >> 16) & 1u);
  return (ushort_t)(r >> 16);
}
__device__ __forceinline__ float fsig(float x){ return 1.f/(1.f + __expf(-x)); }
__device__ __forceinline__ float ftanh(float x){ return 2.f/(1.f + __expf(-2.f*x)) - 1.f; }

// LDS-only barrier: does NOT drain vmcnt; global stores/prefetch loads stay in
// flight across the 2560-step serial loop.
__device__ __forceinline__ void ldsbar(){
  asm volatile("s_waitcnt lgkmcnt(0)\n\ts_barrier" ::: "memory");
}

// ---------------- K0a: transpose x [B][C][T] -> xT [B][T][CP] bf16 (pad c=22,23)
__global__ __launch_bounds__(256) void k_transpose_x(const float* __restrict__ x, ushort_t* __restrict__ xT){
  int idx = blockIdx.x*256 + threadIdx.x;
  if (idx >= BB*TT) return;
  int b = idx / TT, t = idx % TT;
  ushort_t* dst = xT + (size_t)idx*CP;
  const float* src = x + (size_t)b*CC*TT + t;
  #pragma unroll
  for (int c=0;c<CC;c++) dst[c] = f2bf(src[(size_t)c*TT]);
  dst[22] = 0; dst[23] = 0;
}

// ---------------- K0b: B0T[dir][n=512][k=160]: k<128 Wh0[k][n]; 128..149 Wx0[k-128][n]; else 0
__global__ __launch_bounds__(256) void k_prep_l0(const float* __restrict__ WxF, const float* __restrict__ WhF,
                                                 const float* __restrict__ WxB, const float* __restrict__ WhB,
                                                 ushort_t* __restrict__ B0T){
  int idx = blockIdx.x*256 + threadIdx.x;
  if (idx >= 2*512*160) return;
  int dir = idx / 81920; int r = idx % 81920; int n = r / 160; int k = r % 160;
  const float* Wh = dir ? WhB : WhF;
  const float* Wx = dir ? WxB : WxF;
  float v = (k < 128) ? Wh[k*512 + n] : (((k-128) < CC) ? Wx[(k-128)*512 + n] : 0.f);
  B0T[idx] = f2bf(v);
}

// ---------------- K0c: B1T[dir][n=256][k=64] = Wh1[k][n]
__global__ __launch_bounds__(256) void k_prep_l1(const float* __restrict__ WhF, const float* __restrict__ WhB,
                                                 ushort_t* __restrict__ B1T){
  int idx = blockIdx.x*256 + threadIdx.x;
  if (idx >= 2*256*64) return;
  int dir = idx >> 14; int r = idx & 16383; int n = r >> 6; int k = r & 63;
  const float* Wh = dir ? WhB : WhF;
  B1T[idx] = f2bf(Wh[k*256 + n]);
}

// ---------------- K0d: WT[dir][n=256][k=256] = Wx1[k][n]  (for xz1 gemm)
__global__ __launch_bounds__(256) void k_prep_wxT(const float* __restrict__ Wf, const float* __restrict__ Wb,
                                                  ushort_t* __restrict__ WT){
  int idx = blockIdx.x*256 + threadIdx.x;
  int dir = idx >> 16; int r = idx & 65535; int n = r >> 8; int k = r & 255;
  const float* W = dir ? Wb : Wf;
  WT[idx] = f2bf(W[k*256 + n]);
}

// ---------------- K1: layer-0 MFMA scan. 4 chains/WG (C-rows {0,4,8,12}), 4 waves, 32 WGs.
// Wave wv owns n-tiles {g*8 + wv*2 + h : g=0..3, h=0..1} -> lane (m,q) computes both
// gate-sets for units u=wv*32+h*16+m, chain q. Weights register-resident (160 VGPR).
__global__ __launch_bounds__(256, 1) void k_lstm0m(
  const ushort_t* __restrict__ xT, const ushort_t* __restrict__ B0T,
  const float* __restrict__ bF, const float* __restrict__ bB,
  ushort_t* __restrict__ h0seq)                     // [B][T][256]: fwd 0..127, bwd 128..255
{
  const int dir = blockIdx.x & 1, cb = blockIdx.x >> 1;   // cb 0..15
  const int tid = threadIdx.x;
  const int wv = tid >> 6, lane = tid & 63, m = lane & 15, q = lane >> 4;
  const int u0 = wv*32 + m, u1 = u0 + 16;
  const float* bi = dir ? bB : bF;

  __shared__ __align__(16) ushort_t Abuf[2][16][168];  // rows 4q: [h 0..127 | x 128..151 | 0]

  bf16x8 Bf[4][2][5];                                  // [gate][h][ktile]
  const ushort_t* Bb = B0T + (size_t)dir*512*160;
  #pragma unroll
  for (int g=0; g<4; g++)
    #pragma unroll
    for (int h=0; h<2; h++){
      int nt = g*8 + wv*2 + h;
      #pragma unroll
      for (int kt=0; kt<5; kt++)
        Bf[g][h][kt] = *(const bf16x8*)(Bb + (size_t)(nt*16+m)*160 + kt*32 + q*8);
    }
  float bz[4][2];
  #pragma unroll
  for (int g=0; g<4; g++){ bz[g][0] = bi[g*128 + u0]; bz[g][1] = bi[g*128 + u1]; }

  for (int i = tid; i < (int)(sizeof(Abuf)/4); i += 256) ((uint32_t*)Abuf)[i] = 0u;
  __syncthreads();

  // x staging: tid<96 = 4 chains x 24 channels (waves 0..1)
  int chain = 0, cx = 0; const ushort_t* xrow = nullptr;
  ushort_t xreg = 0, xreg2 = 0;
  if (tid < 96){
    chain = tid / 24; cx = tid - chain*24;
    xrow = xT + ((size_t)(cb*4 + chain)*TT)*CP + cx;
    int t0 = dir ? TT-1 : 0;
    int t1 = dir ? TT-2 : 1;
    int t2 = dir ? TT-3 : 2;
    Abuf[0][chain*4][128+cx] = xrow[(size_t)t0*CP];
    xreg  = xrow[(size_t)t1*CP];
    xreg2 = xrow[(size_t)t2*CP];
  }
  __syncthreads();

  float cst0 = 0.f, cst1 = 0.f;
  const int t00 = dir ? TT-1 : 0;
  ushort_t* hp0 = h0seq + ((size_t)(cb*4 + q)*TT + t00)*256 + dir*128 + u0;
  ushort_t* hp1 = h0seq + ((size_t)(cb*4 + q)*TT + t00)*256 + dir*128 + u1;
  const int hstep = dir ? -256 : 256;

  for (int s = 0; s < TT; ++s){
    const int cur = s & 1, nxt = cur ^ 1;

    bf16x8 Af[5];
    const ushort_t* ar = &Abuf[cur][m][0];
    #pragma unroll
    for (int kt=0; kt<5; kt++) Af[kt] = *(const bf16x8*)(ar + kt*32 + q*8);

    floatx4 a[4][2];
    #pragma unroll
    for (int g=0; g<4; g++)
      #pragma unroll
      for (int h=0; h<2; h++){ float b_ = bz[g][h]; a[g][h] = (floatx4){b_,b_,b_,b_}; }

    #pragma unroll
    for (int kt=0; kt<5; kt++)
      #pragma unroll
      for (int g=0; g<4; g++)
        #pragma unroll
        for (int h=0; h<2; h++)
          a[g][h] = __builtin_amdgcn_mfma_f32_16x16x32_bf16(Af[kt], Bf[g][h][kt], a[g][h], 0,0,0);

    ushort_t xnew = 0;
    if (tid < 96){                        // depth-2 x prefetch (never drained at barrier)
      int sn = s + 3; if (sn > TT-1) sn = TT-1;
      int tn = dir ? (TT-1-sn) : sn;
      xnew = xrow[(size_t)tn*CP];
    }

    {  // gate-set h=0 (unit u0, chain q)
      float ig = fsig(a[0][0][0]);
      float fg = fsig(a[1][0][0]);
      float gg = ftanh(a[2][0][0]);
      float og = fsig(a[3][0][0]);
      float cc = fg*cst0 + ig*gg;
      cst0 = cc;
      ushort_t hv = f2bf(og*ftanh(cc));
      Abuf[nxt][q*4][u0] = hv;
      *hp0 = hv; hp0 += hstep;
    }
    {  // gate-set h=1 (unit u1, chain q)
      float ig = fsig(a[0][1][0]);
      float fg = fsig(a[1][1][0]);
      float gg = ftanh(a[2][1][0]);
      float og = fsig(a[3][1][0]);
      float cc = fg*cst1 + ig*gg;
      cst1 = cc;
      ushort_t hv = f2bf(og*ftanh(cc));
      Abuf[nxt][q*4][u1] = hv;
      *hp1 = hv; hp1 += hstep;
    }
    if (tid < 96){
      Abuf[nxt][chain*4][128+cx] = xreg;
      xreg = xreg2; xreg2 = xnew;
    }
    ldsbar();
  }
}

// ---------------- K2: xz1R[dir][b][t][wv][m][g] = bf16( h0seq[bt][:256] @ Wx1[dir] )
// (lane-exact layout for k_lstm1m: per (b,t), unit u=wv*16+mm holds its 4 gate-z's
//  contiguously at offset (wv*16+mm)*4 ushorts)
__global__ __launch_bounds__(512) void k_xz1_gemm(const ushort_t* __restrict__ h0seq,
                                                  const ushort_t* __restrict__ WxT,
                                                  ushort_t* __restrict__ xz1)
{
  const int mb  = blockIdx.x;
  const int dir = blockIdx.y;
  const ushort_t* W   = WxT + (size_t)dir*256*256;
  ushort_t*       out = xz1 + (size_t)dir*BB*TT*256;
  const int wave = threadIdx.x >> 6;
  const int lane = threadIdx.x & 63;
  const int mw = wave & 3;
  const int nw = wave >> 2;       // n-half: gates {2nw, 2nw+1}
  const int m_ = lane & 15;
  const int q_ = lane >> 4;

  floatx4 acc[2][8];
  #pragma unroll
  for (int a=0;a<2;a++)
    #pragma unroll
    for (int n=0;n<8;n++) acc[a][n] = (floatx4)0.f;

  const size_t Abase = ((size_t)mb*128 + mw*32 + m_)*256 + q_*8;
  const size_t Bbase = ((size_t)nw*128 + m_)*256 + q_*8;

  for (int kc = 0; kc < 256; kc += 32){
    bf16x8 afr[2];
    #pragma unroll
    for (int mt=0;mt<2;mt++)
      afr[mt] = *(const bf16x8*)(h0seq + Abase + (size_t)mt*16*256 + kc);
    #pragma unroll
    for (int nt=0;nt<8;nt++){
      bf16x8 bfr = *(const bf16x8*)(W + Bbase + (size_t)nt*16*256 + kc);
      #pragma unroll
      for (int mt=0;mt<2;mt++)
        acc[mt][nt] = __builtin_amdgcn_mfma_f32_16x16x32_bf16(afr[mt], bfr, acc[mt][nt], 0,0,0);
    }
  }
  // epilogue: n = nw*128 + nt*16 + m_ -> g = 2nw + (nt>>2), wvz = nt&3, unit slot = wvz*16+m_
  #pragma unroll
  for (int mt=0;mt<2;mt++)
    #pragma unroll
    for (int r=0;r<4;r++){
      size_t bt = (size_t)mb*128 + mw*32 + mt*16 + q_*4 + r;
      ushort_t* rowp = out + bt*256;
      #pragma unroll
      for (int wvz=0; wvz<4; wvz++){
        uint32_t lo = f2bf(acc[mt][wvz][r]);
        uint32_t hi = f2bf(acc[mt][wvz+4][r]);
        *(uint32_t*)(rowp + (wvz*16+m_)*4 + 2*nw) = lo | (hi << 16);
      }
    }
}

// ---------------- K3: layer-1 MFMA scan. 4 chains/WG, 4 waves, 32 WGs.
// xz read directly from xz1R as one uint2 per lane per step (no LDS staging).
__global__ __launch_bounds__(256, 1) void k_lstm1m(
  const ushort_t* __restrict__ xz1R,                // [dir][b][t][wv][m][g] bf16
  const ushort_t* __restrict__ B1T,                 // [dir][n=256][k=64] bf16
  const float* __restrict__ bF, const float* __restrict__ bB,
  float* __restrict__ h1last)                       // [B][128]: fwd 0..63, bwd 64..127
{
  const int dir = blockIdx.x & 1, cb = blockIdx.x >> 1;   // cb 0..15
  const int tid = threadIdx.x;
  const int wv = tid >> 6, lane = tid & 63, m = lane & 15, q = lane >> 4;
  const int u = wv*16 + m;                                // unit 0..63
  const float* bi = dir ? bB : bF;

  __shared__ __align__(16) ushort_t Hbuf[2][16][88];

  bf16x8 Bf[4][2];                        // gate g -> n-tile g*4+wv
  const ushort_t* Bb = B1T + (size_t)dir*256*64;
  #pragma unroll
  for (int g=0; g<4; g++){
    int nt = g*4 + wv;
    #pragma unroll
    for (int kt=0; kt<2; kt++)
      Bf[g][kt] = *(const bf16x8*)(Bb + (size_t)(nt*16+m)*64 + kt*32 + q*8);
  }
  float bz[4];
  #pragma unroll
  for (int g=0; g<4; g++) bz[g] = bi[g*64 + u];

  for (int i = tid; i < (int)(sizeof(Hbuf)/4); i += 256) ((uint32_t*)Hbuf)[i] = 0u;

  // per-lane xz stream: chain b = cb*4+q, slot (wv*16+m)
  const ushort_t* xzr = xz1R + ((size_t)dir*BB + (size_t)(cb*4+q))*TT*256 + (size_t)(wv*16+m)*4;
  uint2 p0, p1, p2;
  {
    int t0 = dir ? TT-1 : 0;
    int t1 = dir ? TT-2 : 1;
    int t2 = dir ? TT-3 : 2;
    p0 = *(const uint2*)(xzr + (size_t)t0*256);
    p1 = *(const uint2*)(xzr + (size_t)t1*256);
    p2 = *(const uint2*)(xzr + (size_t)t2*256);
  }
  __syncthreads();

  float cst = 0.f, hl = 0.f;

  for (int s = 0; s < TT; ++s){
    const int cur = s & 1, nxt = cur ^ 1;

    bf16x8 Af[2];
    const ushort_t* ar = &Hbuf[cur][m][0];
    Af[0] = *(const bf16x8*)(ar + q*8);
    Af[1] = *(const bf16x8*)(ar + 32 + q*8);

    floatx4 a0 = {bz[0],bz[0],bz[0],bz[0]};
    floatx4 a1 = {bz[1],bz[1],bz[1],bz[1]};
    floatx4 a2 = {bz[2],bz[2],bz[2],bz[2]};
    floatx4 a3 = {bz[3],bz[3],bz[3],bz[3]};
    #pragma unroll
    for (int kt=0; kt<2; kt++){
      a0 = __builtin_amdgcn_mfma_f32_16x16x32_bf16(Af[kt], Bf[0][kt], a0, 0,0,0);
      a1 = __builtin_amdgcn_mfma_f32_16x16x32_bf16(Af[kt], Bf[1][kt], a1, 0,0,0);
      a2 = __builtin_amdgcn_mfma_f32_16x16x32_bf16(Af[kt], Bf[2][kt], a2, 0,0,0);
      a3 = __builtin_amdgcn_mfma_f32_16x16x32_bf16(Af[kt], Bf[3][kt], a3, 0,0,0);
    }

    // consume prefetched xz(t(s)); then rotate and issue load for s+3
    float z0 = a0[0] + bf2f((ushort_t)(p0.x & 0xffff));
    float z1 = a1[0] + bf2f((ushort_t)(p0.x >> 16));
    float z2 = a2[0] + bf2f((ushort_t)(p0.y & 0xffff));
    float z3 = a3[0] + bf2f((ushort_t)(p0.y >> 16));
    p0 = p1; p1 = p2;
    {
      int sn = s + 3; if (sn > TT-1) sn = TT-1;
      int tn = dir ? (TT-1-sn) : sn;
      p2 = *(const uint2*)(xzr + (size_t)tn*256);
    }

    {
      float ig = fsig(z0), fg = fsig(z1), og = fsig(z3);
      float gg = ftanh(z2);
      float cc = fg*cst + ig*gg;
      cst = cc;
      hl = og*ftanh(cc);
      Hbuf[nxt][q*4][u] = f2bf(hl);
    }
    ldsbar();
  }
  h1last[(size_t)(cb*4 + q)*128 + dir*64 + u] = hl;
}

// ---------------- K4: dense head
__global__ __launch_bounds__(128) void k_head(
  const float* __restrict__ h1last,
  const float* __restrict__ d0W, const float* __restrict__ d0b,
  const float* __restrict__ d1W, const float* __restrict__ d1b,
  const float* __restrict__ oW,  const float* __restrict__ ob,
  float* __restrict__ outp)
{
  const int b = blockIdx.x;
  const int j = threadIdx.x;
  __shared__ float v0[128], v1[128];
  v0[j] = h1last[b*128 + j];
  __syncthreads();
  float acc = d0b[j];
  #pragma unroll
  for (int k=0;k<128;k++) acc += v0[k]*d0W[k*128 + j];
  v1[j] = fmaxf(acc, 0.f);
  __syncthreads();
  if (j < 64){
    float a2 = d1b[j];
    #pragma unroll
    for (int k=0;k<128;k++) a2 += v1[k]*d1W[k*64 + j];
    float p = fmaxf(a2, 0.f) * oW[j];
    #pragma unroll
    for (int off=32; off>0; off>>=1) p += __shfl_down(p, off, 64);
    if (j == 0) outp[b] = 1.f/(1.f + __expf(-(p + ob[0])));
  }
}

extern "C" void kernel_launch(void* const* d_in, const int* in_sizes, int n_in,
                              void* d_out, int out_size, void* d_ws, size_t ws_size,
                              hipStream_t stream)
{
  const float* x     = (const float*)d_in[0];
  const float* l0fWx = (const float*)d_in[1];
  const float* l0fWh = (const float*)d_in[2];
  const float* l0fb  = (const float*)d_in[3];
  const float* l0bWx = (const float*)d_in[4];
  const float* l0bWh = (const float*)d_in[5];
  const float* l0bb  = (const float*)d_in[6];
  const float* l1fWx = (const float*)d_in[7];
  const float* l1fWh = (const float*)d_in[8];
  const float* l1fb  = (const float*)d_in[9];
  const float* l1bWx = (const float*)d_in[10];
  const float* l1bWh = (const float*)d_in[11];
  const float* l1bb  = (const float*)d_in[12];
  const float* d0W = (const float*)d_in[13];
  const float* d0b = (const float*)d_in[14];
  const float* d1W = (const float*)d_in[15];
  const float* d1b = (const float*)d_in[16];
  const float* oW  = (const float*)d_in[17];
  const float* ob  = (const float*)d_in[18];
  float* outp = (float*)d_out;

  char* ws = (char*)d_ws;
  const size_t OFF_XT  = 0;                        // 7,864,320
  const size_t OFF_H0  = OFF_XT  + 7864320ull;     // 83,886,080
  const size_t OFF_XZ  = OFF_H0  + 83886080ull;    // 167,772,160 (xz1R)
  const size_t OFF_WT  = OFF_XZ  + 167772160ull;   // 262,144
  const size_t OFF_B0  = OFF_WT  + 262144ull;      // 327,680
  const size_t OFF_B1  = OFF_B0  + 327680ull;      // 65,536
  const size_t OFF_H1  = OFF_B1  + 65536ull;       // 32,768

  ushort_t* xT  = (ushort_t*)(ws + OFF_XT);
  ushort_t* h0  = (ushort_t*)(ws + OFF_H0);
  ushort_t* xz1 = (ushort_t*)(ws + OFF_XZ);
  ushort_t* WT  = (ushort_t*)(ws + OFF_WT);
  ushort_t* B0T = (ushort_t*)(ws + OFF_B0);
  ushort_t* B1T = (ushort_t*)(ws + OFF_B1);
  float*    h1l = (float*)(ws + OFF_H1);

  hipLaunchKernelGGL(k_transpose_x, dim3(640), dim3(256), 0, stream, x, xT);
  hipLaunchKernelGGL(k_prep_l0,     dim3(640), dim3(256), 0, stream, l0fWx, l0fWh, l0bWx, l0bWh, B0T);
  hipLaunchKernelGGL(k_prep_l1,     dim3(128), dim3(256), 0, stream, l1fWh, l1bWh, B1T);
  hipLaunchKernelGGL(k_prep_wxT,    dim3(512), dim3(256), 0, stream, l1fWx, l1bWx, WT);
  hipLaunchKernelGGL(k_lstm0m,      dim3(32),  dim3(256), 0, stream, xT, B0T, l0fb, l0bb, h0);
  hipLaunchKernelGGL(k_xz1_gemm,    dim3(1280,2), dim3(512), 0, stream, h0, WT, xz1);
  hipLaunchKernelGGL(k_lstm1m,      dim3(32),  dim3(256), 0, stream, xz1, B1T, l1fb, l1bb, h1l);
  hipLaunchKernelGGL(k_head,        dim3(64),  dim3(128), 0, stream,
                     h1l, d0W, d0b, d1W, d1b, oW, ob, outp);
}

// Round 6
// 2894.464 us; speedup vs baseline: 1.7497x; 1.1277x over previous
//
#include <hip/hip_runtime.h>
#include <stdint.h>

#define TT 2560
#define BB 64
#define CC 22
#define CP 24

typedef unsigned short ushort_t;
typedef __attribute__((ext_vector_type(4))) float floatx4;
typedef __attribute__((ext_vector_type(8))) short bf16x8;

__device__ __forceinline__ float bf2f(ushort_t u){
  union { uint32_t i; float f; } v; v.i = ((uint32_t)u) << 16; return v.f;
}
__device__ __forceinline__ ushort_t f2bf(float f){
  union { float f; uint32_t i; } v; v.f = f;
  uint32_t r = v.i + 0x7FFFu + ((v.i >> 16) & 1u);
  return (ushort_t)(r >> 16);
}
__device__ __forceinline__ float fsig(float x){ return 1.f/(1.f + __expf(-x)); }
__device__ __forceinline__ float ftanh(float x){ return 2.f/(1.f + __expf(-2.f*x)) - 1.f; }

// LDS-only barrier: does NOT drain vmcnt; global stores/prefetch loads stay in
// flight across the 2560-step serial loop.
__device__ __forceinline__ void ldsbar(){
  asm volatile("s_waitcnt lgkmcnt(0)\n\ts_barrier" ::: "memory");
}

// reverse 8 packed bf16 (for backward-direction time chunks)
__device__ __forceinline__ uint4 rev8(uint4 v){
  uint4 r;
  r.x = (v.w >> 16) | (v.w << 16);
  r.y = (v.z >> 16) | (v.z << 16);
  r.z = (v.y >> 16) | (v.y << 16);
  r.w = (v.x >> 16) | (v.x << 16);
  return r;
}
// compile-time element extract (j in 0..7)
__device__ __forceinline__ ushort_t elem8(uint4 v, int j){
  uint32_t d = ((j>>1)==0) ? v.x : ((j>>1)==1) ? v.y : ((j>>1)==2) ? v.z : v.w;
  return (ushort_t)((j&1) ? (d>>16) : (d & 0xffffu));
}

// ---------------- K0a: cast x [B][C][T] fp32 -> xc [B][C][T] bf16 (time-contiguous!)
__global__ __launch_bounds__(256) void k_convert_x(const float* __restrict__ x, ushort_t* __restrict__ xc){
  int i4 = blockIdx.x*256 + threadIdx.x;      // 0 .. 901119 (x4 elements)
  if (i4 >= BB*CC*TT/4) return;
  const float4 v = ((const float4*)x)[i4];
  uint2 o;
  o.x = (uint32_t)f2bf(v.x) | ((uint32_t)f2bf(v.y) << 16);
  o.y = (uint32_t)f2bf(v.z) | ((uint32_t)f2bf(v.w) << 16);
  ((uint2*)xc)[i4] = o;
}

// ---------------- K0b: B0T[dir][n=512][k=160]: k<128 Wh0[k][n]; 128..149 Wx0[k-128][n]; else 0
__global__ __launch_bounds__(256) void k_prep_l0(const float* __restrict__ WxF, const float* __restrict__ WhF,
                                                 const float* __restrict__ WxB, const float* __restrict__ WhB,
                                                 ushort_t* __restrict__ B0T){
  int idx = blockIdx.x*256 + threadIdx.x;
  if (idx >= 2*512*160) return;
  int dir = idx / 81920; int r = idx % 81920; int n = r / 160; int k = r % 160;
  const float* Wh = dir ? WhB : WhF;
  const float* Wx = dir ? WxB : WxF;
  float v = (k < 128) ? Wh[k*512 + n] : (((k-128) < CC) ? Wx[(k-128)*512 + n] : 0.f);
  B0T[idx] = f2bf(v);
}

// ---------------- K0c: B1T[dir][n=256][k=64] = Wh1[k][n]
__global__ __launch_bounds__(256) void k_prep_l1(const float* __restrict__ WhF, const float* __restrict__ WhB,
                                                 ushort_t* __restrict__ B1T){
  int idx = blockIdx.x*256 + threadIdx.x;
  if (idx >= 2*256*64) return;
  int dir = idx >> 14; int r = idx & 16383; int n = r >> 6; int k = r & 63;
  const float* Wh = dir ? WhB : WhF;
  B1T[idx] = f2bf(Wh[k*256 + n]);
}

// ---------------- K0d: WT[dir][n=256][k=256] = Wx1[k][n]  (for xz1 gemm)
__global__ __launch_bounds__(256) void k_prep_wxT(const float* __restrict__ Wf, const float* __restrict__ Wb,
                                                  ushort_t* __restrict__ WT){
  int idx = blockIdx.x*256 + threadIdx.x;
  int dir = idx >> 16; int r = idx & 65535; int n = r >> 8; int k = r & 255;
  const float* W = dir ? Wb : Wf;
  WT[idx] = f2bf(W[k*256 + n]);
}

// ---------------- K1: layer-0 MFMA scan. 4 chains/WG (C-rows {0,4,8,12}), 4 waves, 32 WGs.
// Unrolled x8; x arrives via a 3-chunk register pipeline (loads 8 steps ahead of use).
__global__ __launch_bounds__(256, 1) void k_lstm0m(
  const ushort_t* __restrict__ xc, const ushort_t* __restrict__ B0T,
  const float* __restrict__ bF, const float* __restrict__ bB,
  ushort_t* __restrict__ h0seq)                     // [B][T][256]: fwd 0..127, bwd 128..255
{
  const int dir = blockIdx.x & 1, cb = blockIdx.x >> 1;   // cb 0..15
  const int tid = threadIdx.x;
  const int wv = tid >> 6, lane = tid & 63, m = lane & 15, q = lane >> 4;
  const int u0 = wv*32 + m, u1 = u0 + 16;
  const float* bi = dir ? bB : bF;

  __shared__ __align__(16) ushort_t Abuf[2][16][168];  // rows 4q: [h 0..127 | x 128..149 | 0]

  bf16x8 Bf[4][2][5];                                  // [gate][h][ktile] register-resident
  const ushort_t* Bb = B0T + (size_t)dir*512*160;
  #pragma unroll
  for (int g=0; g<4; g++)
    #pragma unroll
    for (int h=0; h<2; h++){
      int nt = g*8 + wv*2 + h;
      #pragma unroll
      for (int kt=0; kt<5; kt++)
        Bf[g][h][kt] = *(const bf16x8*)(Bb + (size_t)(nt*16+m)*160 + kt*32 + q*8);
    }
  float bz[4][2];
  #pragma unroll
  for (int g=0; g<4; g++){ bz[g][0] = bi[g*128 + u0]; bz[g][1] = bi[g*128 + u1]; }

  for (int i = tid; i < (int)(sizeof(Abuf)/4); i += 256) ((uint32_t*)Abuf)[i] = 0u;
  __syncthreads();

  // x staging pipeline: 88 threads = 4 chains x 22 channels
  const bool stg = (tid < 88);
  int ch = 0, cx = 0; const ushort_t* xrow = nullptr;
  uint4 curR = {0,0,0,0}, nextR = {0,0,0,0}, infl = {0,0,0,0};
  if (stg){
    ch = tid / 22; cx = tid - ch*22;
    xrow = xc + ((size_t)(cb*4 + ch)*CC + cx)*TT;    // time-contiguous row
    // prefill Abuf[0] with x(step 0)
    Abuf[0][ch*4][128+cx] = xrow[dir ? TT-1 : 0];
    // chunk c0 -> nextR (reversed for bwd), chunk c1 -> infl
    int t0a = dir ? (TT-8) : 0;
    int t0b = dir ? (TT-16) : 8;
    uint4 L0 = *(const uint4*)(xrow + t0a);
    nextR = dir ? rev8(L0) : L0;
    infl  = *(const uint4*)(xrow + t0b);
  }
  __syncthreads();

  float cst[2] = {0.f, 0.f};
  const int t00 = dir ? TT-1 : 0;
  ushort_t* hp0 = h0seq + ((size_t)(cb*4 + q)*TT + t00)*256 + dir*128 + u0;
  ushort_t* hp1 = h0seq + ((size_t)(cb*4 + q)*TT + t00)*256 + dir*128 + u1;
  const int hstep = dir ? -256 : 256;

  for (int i = 0; i < TT/8; ++i){
    // chunk rotation: waits target loads issued 8 steps (~4000 cy) ago
    if (stg){
      curR = nextR;
      nextR = dir ? rev8(infl) : infl;
      int ci = i + 2; if (ci > TT/8 - 1) ci = TT/8 - 1;
      int t0 = dir ? (TT - 8 - 8*ci) : 8*ci;
      infl = *(const uint4*)(xrow + t0);
    }
    #pragma unroll
    for (int p = 0; p < 8; ++p){
      const int cur = p & 1, nxt = cur ^ 1;

      bf16x8 Af[5];
      const ushort_t* ar = &Abuf[cur][m][0];
      #pragma unroll
      for (int kt=0; kt<5; kt++) Af[kt] = *(const bf16x8*)(ar + kt*32 + q*8);

      floatx4 a[4][2];
      #pragma unroll
      for (int g=0; g<4; g++)
        #pragma unroll
        for (int h=0; h<2; h++){ float b_ = bz[g][h]; a[g][h] = (floatx4){b_,b_,b_,b_}; }

      #pragma unroll
      for (int kt=0; kt<5; kt++)
        #pragma unroll
        for (int g=0; g<4; g++)
          #pragma unroll
          for (int h=0; h<2; h++)
            a[g][h] = __builtin_amdgcn_mfma_f32_16x16x32_bf16(Af[kt], Bf[g][h][kt], a[g][h], 0,0,0);

      {  // gate-set h=0 (unit u0, chain q)
        float ig = fsig(a[0][0][0]);
        float fg = fsig(a[1][0][0]);
        float gg = ftanh(a[2][0][0]);
        float og = fsig(a[3][0][0]);
        float cc = fg*cst[0] + ig*gg;
        cst[0] = cc;
        ushort_t hv = f2bf(og*ftanh(cc));
        Abuf[nxt][q*4][u0] = hv;
        *hp0 = hv; hp0 += hstep;
      }
      {  // gate-set h=1 (unit u1, chain q)
        float ig = fsig(a[0][1][0]);
        float fg = fsig(a[1][1][0]);
        float gg = ftanh(a[2][1][0]);
        float og = fsig(a[3][1][0]);
        float cc = fg*cst[1] + ig*gg;
        cst[1] = cc;
        ushort_t hv = f2bf(og*ftanh(cc));
        Abuf[nxt][q*4][u1] = hv;
        *hp1 = hv; hp1 += hstep;
      }
      if (stg){
        // publish x(step s+1): phases 0..6 from curR[p+1], phase 7 from nextR[0]
        ushort_t xp = (p < 7) ? elem8(curR, p+1) : elem8(nextR, 0);
        Abuf[nxt][ch*4][128+cx] = xp;
      }
      ldsbar();
    }
  }
}

// ---------------- K2: xz1R[dir][b][t][u(64)][g(4)] = bf16( h0seq[bt][:256] @ Wx1[dir] )
// lane-exact layout: per (b,t), unit u holds its 4 gate-z's contiguously at offset u*4
__global__ __launch_bounds__(512) void k_xz1_gemm(const ushort_t* __restrict__ h0seq,
                                                  const ushort_t* __restrict__ WxT,
                                                  ushort_t* __restrict__ xz1)
{
  const int mb  = blockIdx.x;
  const int dir = blockIdx.y;
  const ushort_t* W   = WxT + (size_t)dir*256*256;
  ushort_t*       out = xz1 + (size_t)dir*BB*TT*256;
  const int wave = threadIdx.x >> 6;
  const int lane = threadIdx.x & 63;
  const int mw = wave & 3;
  const int nw = wave >> 2;       // n-half: gates {2nw, 2nw+1}
  const int m_ = lane & 15;
  const int q_ = lane >> 4;

  floatx4 acc[2][8];
  #pragma unroll
  for (int a=0;a<2;a++)
    #pragma unroll
    for (int n=0;n<8;n++) acc[a][n] = (floatx4)0.f;

  const size_t Abase = ((size_t)mb*128 + mw*32 + m_)*256 + q_*8;
  const size_t Bbase = ((size_t)nw*128 + m_)*256 + q_*8;

  for (int kc = 0; kc < 256; kc += 32){
    bf16x8 afr[2];
    #pragma unroll
    for (int mt=0;mt<2;mt++)
      afr[mt] = *(const bf16x8*)(h0seq + Abase + (size_t)mt*16*256 + kc);
    #pragma unroll
    for (int nt=0;nt<8;nt++){
      bf16x8 bfr = *(const bf16x8*)(W + Bbase + (size_t)nt*16*256 + kc);
      #pragma unroll
      for (int mt=0;mt<2;mt++)
        acc[mt][nt] = __builtin_amdgcn_mfma_f32_16x16x32_bf16(afr[mt], bfr, acc[mt][nt], 0,0,0);
    }
  }
  // epilogue: n = nw*128 + nt*16 + m_ -> g = 2nw + (nt>>2), wvz = nt&3, unit = wvz*16+m_
  #pragma unroll
  for (int mt=0;mt<2;mt++)
    #pragma unroll
    for (int r=0;r<4;r++){
      size_t bt = (size_t)mb*128 + mw*32 + mt*16 + q_*4 + r;
      ushort_t* rowp = out + bt*256;
      #pragma unroll
      for (int wvz=0; wvz<4; wvz++){
        uint32_t lo = f2bf(acc[mt][wvz][r]);
        uint32_t hi = f2bf(acc[mt][wvz+4][r]);
        *(uint32_t*)(rowp + (wvz*16+m_)*4 + 2*nw) = lo | (hi << 16);
      }
    }
}

// ---------------- K3: layer-1 MFMA scan. 4 chains/WG, 4 waves, 32 WGs. Unrolled x4;
// per-lane xz stream prefetched 4 steps ahead (pz[p] reloaded only after consumption).
__global__ __launch_bounds__(256, 1) void k_lstm1m(
  const ushort_t* __restrict__ xz1R,                // [dir][b][t][u][g] bf16
  const ushort_t* __restrict__ B1T,                 // [dir][n=256][k=64] bf16
  const float* __restrict__ bF, const float* __restrict__ bB,
  float* __restrict__ h1last)                       // [B][128]: fwd 0..63, bwd 64..127
{
  const int dir = blockIdx.x & 1, cb = blockIdx.x >> 1;   // cb 0..15
  const int tid = threadIdx.x;
  const int wv = tid >> 6, lane = tid & 63, m = lane & 15, q = lane >> 4;
  const int u = wv*16 + m;                                // unit 0..63
  const float* bi = dir ? bB : bF;

  __shared__ __align__(16) ushort_t Hbuf[2][16][88];

  bf16x8 Bf[4][2];                        // gate g -> n-tile g*4+wv
  const ushort_t* Bb = B1T + (size_t)dir*256*64;
  #pragma unroll
  for (int g=0; g<4; g++){
    int nt = g*4 + wv;
    #pragma unroll
    for (int kt=0; kt<2; kt++)
      Bf[g][kt] = *(const bf16x8*)(Bb + (size_t)(nt*16+m)*64 + kt*32 + q*8);
  }
  float bz[4];
  #pragma unroll
  for (int g=0; g<4; g++) bz[g] = bi[g*64 + u];

  for (int i = tid; i < (int)(sizeof(Hbuf)/4); i += 256) ((uint32_t*)Hbuf)[i] = 0u;

  // per-lane xz stream: chain b = cb*4+q, slot u
  const ushort_t* xzr = xz1R + ((size_t)dir*BB + (size_t)(cb*4+q))*TT*256 + (size_t)u*4;
  uint2 pz[4];
  #pragma unroll
  for (int j=0; j<4; j++){
    int tj = dir ? (TT-1-j) : j;
    pz[j] = *(const uint2*)(xzr + (size_t)tj*256);
  }
  __syncthreads();

  float cst = 0.f, hl = 0.f;

  for (int i = 0; i < TT/4; ++i){
    #pragma unroll
    for (int p = 0; p < 4; ++p){
      const int s = i*4 + p;
      const int cur = p & 1, nxt = cur ^ 1;

      bf16x8 Af[2];
      const ushort_t* ar = &Hbuf[cur][m][0];
      Af[0] = *(const bf16x8*)(ar + q*8);
      Af[1] = *(const bf16x8*)(ar + 32 + q*8);

      floatx4 a0 = {bz[0],bz[0],bz[0],bz[0]};
      floatx4 a1 = {bz[1],bz[1],bz[1],bz[1]};
      floatx4 a2 = {bz[2],bz[2],bz[2],bz[2]};
      floatx4 a3 = {bz[3],bz[3],bz[3],bz[3]};
      #pragma unroll
      for (int kt=0; kt<2; kt++){
        a0 = __builtin_amdgcn_mfma_f32_16x16x32_bf16(Af[kt], Bf[0][kt], a0, 0,0,0);
        a1 = __builtin_amdgcn_mfma_f32_16x16x32_bf16(Af[kt], Bf[1][kt], a1, 0,0,0);
        a2 = __builtin_amdgcn_mfma_f32_16x16x32_bf16(Af[kt], Bf[2][kt], a2, 0,0,0);
        a3 = __builtin_amdgcn_mfma_f32_16x16x32_bf16(Af[kt], Bf[3][kt], a3, 0,0,0);
      }

      // consume pz[p] (loaded 4 steps ago), then reload it for step s+4
      float z0 = a0[0] + bf2f((ushort_t)(pz[p].x & 0xffff));
      float z1 = a1[0] + bf2f((ushort_t)(pz[p].x >> 16));
      float z2 = a2[0] + bf2f((ushort_t)(pz[p].y & 0xffff));
      float z3 = a3[0] + bf2f((ushort_t)(pz[p].y >> 16));
      {
        int sn = s + 4; if (sn > TT-1) sn = TT-1;
        int tn = dir ? (TT-1-sn) : sn;
        pz[p] = *(const uint2*)(xzr + (size_t)tn*256);
      }

      {
        float ig = fsig(z0), fg = fsig(z1), og = fsig(z3);
        float gg = ftanh(z2);
        float cc = fg*cst + ig*gg;
        cst = cc;
        hl = og*ftanh(cc);
        Hbuf[nxt][q*4][u] = f2bf(hl);
      }
      ldsbar();
    }
  }
  h1last[(size_t)(cb*4 + q)*128 + dir*64 + u] = hl;
}

// ---------------- K4: dense head
__global__ __launch_bounds__(128) void k_head(
  const float* __restrict__ h1last,
  const float* __restrict__ d0W, const float* __restrict__ d0b,
  const float* __restrict__ d1W, const float* __restrict__ d1b,
  const float* __restrict__ oW,  const float* __restrict__ ob,
  float* __restrict__ outp)
{
  const int b = blockIdx.x;
  const int j = threadIdx.x;
  __shared__ float v0[128], v1[128];
  v0[j] = h1last[b*128 + j];
  __syncthreads();
  float acc = d0b[j];
  #pragma unroll
  for (int k=0;k<128;k++) acc += v0[k]*d0W[k*128 + j];
  v1[j] = fmaxf(acc, 0.f);
  __syncthreads();
  if (j < 64){
    float a2 = d1b[j];
    #pragma unroll
    for (int k=0;k<128;k++) a2 += v1[k]*d1W[k*64 + j];
    float p = fmaxf(a2, 0.f) * oW[j];
    #pragma unroll
    for (int off=32; off>0; off>>=1) p += __shfl_down(p, off, 64);
    if (j == 0) outp[b] = 1.f/(1.f + __expf(-(p + ob[0])));
  }
}

extern "C" void kernel_launch(void* const* d_in, const int* in_sizes, int n_in,
                              void* d_out, int out_size, void* d_ws, size_t ws_size,
                              hipStream_t stream)
{
  const float* x     = (const float*)d_in[0];
  const float* l0fWx = (const float*)d_in[1];
  const float* l0fWh = (const float*)d_in[2];
  const float* l0fb  = (const float*)d_in[3];
  const float* l0bWx = (const float*)d_in[4];
  const float* l0bWh = (const float*)d_in[5];
  const float* l0bb  = (const float*)d_in[6];
  const float* l1fWx = (const float*)d_in[7];
  const float* l1fWh = (const float*)d_in[8];
  const float* l1fb  = (const float*)d_in[9];
  const float* l1bWx = (const float*)d_in[10];
  const float* l1bWh = (const float*)d_in[11];
  const float* l1bb  = (const float*)d_in[12];
  const float* d0W = (const float*)d_in[13];
  const float* d0b = (const float*)d_in[14];
  const float* d1W = (const float*)d_in[15];
  const float* d1b = (const float*)d_in[16];
  const float* oW  = (const float*)d_in[17];
  const float* ob  = (const float*)d_in[18];
  float* outp = (float*)d_out;

  char* ws = (char*)d_ws;
  const size_t OFF_XT  = 0;                        // xc: 64*22*2560*2 = 7,208,960 (slot 7,864,320)
  const size_t OFF_H0  = OFF_XT  + 7864320ull;     // 83,886,080
  const size_t OFF_XZ  = OFF_H0  + 83886080ull;    // 167,772,160 (xz1R)
  const size_t OFF_WT  = OFF_XZ  + 167772160ull;   // 262,144
  const size_t OFF_B0  = OFF_WT  + 262144ull;      // 327,680
  const size_t OFF_B1  = OFF_B0  + 327680ull;      // 65,536
  const size_t OFF_H1  = OFF_B1  + 65536ull;       // 32,768

  ushort_t* xc  = (ushort_t*)(ws + OFF_XT);
  ushort_t* h0  = (ushort_t*)(ws + OFF_H0);
  ushort_t* xz1 = (ushort_t*)(ws + OFF_XZ);
  ushort_t* WT  = (ushort_t*)(ws + OFF_WT);
  ushort_t* B0T = (ushort_t*)(ws + OFF_B0);
  ushort_t* B1T = (ushort_t*)(ws + OFF_B1);
  float*    h1l = (float*)(ws + OFF_H1);

  hipLaunchKernelGGL(k_convert_x,   dim3(3520), dim3(256), 0, stream, x, xc);
  hipLaunchKernelGGL(k_prep_l0,     dim3(640),  dim3(256), 0, stream, l0fWx, l0fWh, l0bWx, l0bWh, B0T);
  hipLaunchKernelGGL(k_prep_l1,     dim3(128),  dim3(256), 0, stream, l1fWh, l1bWh, B1T);
  hipLaunchKernelGGL(k_prep_wxT,    dim3(512),  dim3(256), 0, stream, l1fWx, l1bWx, WT);
  hipLaunchKernelGGL(k_lstm0m,      dim3(32),   dim3(256), 0, stream, xc, B0T, l0fb, l0bb, h0);
  hipLaunchKernelGGL(k_xz1_gemm,    dim3(1280,2), dim3(512), 0, stream, h0, WT, xz1);
  hipLaunchKernelGGL(k_lstm1m,      dim3(32),   dim3(256), 0, stream, xz1, B1T, l1fb, l1bb, h1l);
  hipLaunchKernelGGL(k_head,        dim3(64),   dim3(128), 0, stream,
                     h1l, d0W, d0b, d1W, d1b, oW, ob, outp);
}

// Round 7
// 2736.108 us; speedup vs baseline: 1.8509x; 1.0579x over previous
//
#include <hip/hip_runtime.h>
#include <stdint.h>

#define TT 2560
#define BB 64
#define CC 22
#define CP 24

typedef unsigned short ushort_t;
typedef __attribute__((ext_vector_type(4))) float floatx4;
typedef __attribute__((ext_vector_type(8))) short bf16x8;

__device__ __forceinline__ float bf2f(ushort_t u){
  union { uint32_t i; float f; } v; v.i = ((uint32_t)u) << 16; return v.f;
}
__device__ __forceinline__ ushort_t f2bf(float f){
  union { float f; uint32_t i; } v; v.f = f;
  uint32_t r = v.i + 0x7FFFu + ((v.i >> 16) & 1u);
  return (ushort_t)(r >> 16);
}
__device__ __forceinline__ float fsig(float x){ return 1.f/(1.f + __expf(-x)); }
__device__ __forceinline__ float ftanh(float x){ return 2.f/(1.f + __expf(-2.f*x)) - 1.f; }

// LDS-only barrier: does NOT drain vmcnt; global stores/prefetch loads stay in
// flight across the 2560-step serial loop.
__device__ __forceinline__ void ldsbar(){
  asm volatile("s_waitcnt lgkmcnt(0)\n\ts_barrier" ::: "memory");
}

// reverse 8 packed bf16 (for backward-direction time chunks)
__device__ __forceinline__ uint4 rev8(uint4 v){
  uint4 r;
  r.x = (v.w >> 16) | (v.w << 16);
  r.y = (v.z >> 16) | (v.z << 16);
  r.z = (v.y >> 16) | (v.y << 16);
  r.w = (v.x >> 16) | (v.x << 16);
  return r;
}
// compile-time element extract (j in 0..7)
__device__ __forceinline__ ushort_t elem8(uint4 v, int j){
  uint32_t d = ((j>>1)==0) ? v.x : ((j>>1)==1) ? v.y : ((j>>1)==2) ? v.z : v.w;
  return (ushort_t)((j&1) ? (d>>16) : (d & 0xffffu));
}

// ---------------- K0a: cast x [B][C][T] fp32 -> xc [B][C][T] bf16 (time-contiguous)
__global__ __launch_bounds__(256) void k_convert_x(const float* __restrict__ x, ushort_t* __restrict__ xc){
  int i4 = blockIdx.x*256 + threadIdx.x;
  if (i4 >= BB*CC*TT/4) return;
  const float4 v = ((const float4*)x)[i4];
  uint2 o;
  o.x = (uint32_t)f2bf(v.x) | ((uint32_t)f2bf(v.y) << 16);
  o.y = (uint32_t)f2bf(v.z) | ((uint32_t)f2bf(v.w) << 16);
  ((uint2*)xc)[i4] = o;
}

// ---------------- K0b: B0T[dir][n=512][k=160]: k<128 Wh0[k][n]; 128..149 Wx0[k-128][n]; else 0
__global__ __launch_bounds__(256) void k_prep_l0(const float* __restrict__ WxF, const float* __restrict__ WhF,
                                                 const float* __restrict__ WxB, const float* __restrict__ WhB,
                                                 ushort_t* __restrict__ B0T){
  int idx = blockIdx.x*256 + threadIdx.x;
  if (idx >= 2*512*160) return;
  int dir = idx / 81920; int r = idx % 81920; int n = r / 160; int k = r % 160;
  const float* Wh = dir ? WhB : WhF;
  const float* Wx = dir ? WxB : WxF;
  float v = (k < 128) ? Wh[k*512 + n] : (((k-128) < CC) ? Wx[(k-128)*512 + n] : 0.f);
  B0T[idx] = f2bf(v);
}

// ---------------- K0c: B1T[dir][n=256][k=64] = Wh1[k][n]
__global__ __launch_bounds__(256) void k_prep_l1(const float* __restrict__ WhF, const float* __restrict__ WhB,
                                                 ushort_t* __restrict__ B1T){
  int idx = blockIdx.x*256 + threadIdx.x;
  if (idx >= 2*256*64) return;
  int dir = idx >> 14; int r = idx & 16383; int n = r >> 6; int k = r & 63;
  const float* Wh = dir ? WhB : WhF;
  B1T[idx] = f2bf(Wh[k*256 + n]);
}

// ---------------- K0d: WT[dir][n=256][k=256] = Wx1[k][n]  (for xz1 gemm)
__global__ __launch_bounds__(256) void k_prep_wxT(const float* __restrict__ Wf, const float* __restrict__ Wb,
                                                  ushort_t* __restrict__ WT){
  int idx = blockIdx.x*256 + threadIdx.x;
  int dir = idx >> 16; int r = idx & 65535; int n = r >> 8; int k = r & 255;
  const float* W = dir ? Wb : Wf;
  WT[idx] = f2bf(W[k*256 + n]);
}

// ---------------- K1: layer-0 MFMA scan. 4 chains/WG, 8 waves (2/SIMD for MFMA<->VALU
// overlap), 32 WGs. Wave wv owns n-tiles {g*8+wv}; lane = 1 gate-set (unit wv*16+m, chain q).
__global__ __launch_bounds__(512, 2) void k_lstm0m(
  const ushort_t* __restrict__ xc, const ushort_t* __restrict__ B0T,
  const float* __restrict__ bF, const float* __restrict__ bB,
  ushort_t* __restrict__ h0seq)                     // [B][T][256]: fwd 0..127, bwd 128..255
{
  const int dir = blockIdx.x & 1, cb = blockIdx.x >> 1;   // cb 0..15
  const int tid = threadIdx.x;
  const int wv = tid >> 6, lane = tid & 63, m = lane & 15, q = lane >> 4;
  const int u = wv*16 + m;                                // unit 0..127
  const float* bi = dir ? bB : bF;

  __shared__ __align__(16) ushort_t Abuf[2][16][168];  // rows 4q: [h 0..127 | x 128..149 | 0]

  bf16x8 Bf[4][5];                                     // [gate][ktile] register-resident
  const ushort_t* Bb = B0T + (size_t)dir*512*160;
  #pragma unroll
  for (int g=0; g<4; g++){
    int nt = g*8 + wv;
    #pragma unroll
    for (int kt=0; kt<5; kt++)
      Bf[g][kt] = *(const bf16x8*)(Bb + (size_t)(nt*16+m)*160 + kt*32 + q*8);
  }
  float bz[4];
  #pragma unroll
  for (int g=0; g<4; g++) bz[g] = bi[g*128 + u];

  for (int i = tid; i < (int)(sizeof(Abuf)/4); i += 512) ((uint32_t*)Abuf)[i] = 0u;
  __syncthreads();

  // x staging pipeline: 88 threads = 4 chains x 22 channels (waves 0..1)
  const bool stg = (tid < 88);
  int ch = 0, cx = 0; const ushort_t* xrow = nullptr;
  uint4 curR = {0,0,0,0}, nextR = {0,0,0,0}, infl = {0,0,0,0};
  if (stg){
    ch = tid / 22; cx = tid - ch*22;
    xrow = xc + ((size_t)(cb*4 + ch)*CC + cx)*TT;
    Abuf[0][ch*4][128+cx] = xrow[dir ? TT-1 : 0];
    int t0a = dir ? (TT-8) : 0;
    int t0b = dir ? (TT-16) : 8;
    uint4 L0 = *(const uint4*)(xrow + t0a);
    nextR = dir ? rev8(L0) : L0;
    infl  = *(const uint4*)(xrow + t0b);
  }
  __syncthreads();

  const floatx4 z4 = {0.f,0.f,0.f,0.f};   // persistent zero C-operand (never written)
  float cst = 0.f;
  const int t00 = dir ? TT-1 : 0;
  ushort_t* hp = h0seq + ((size_t)(cb*4 + q)*TT + t00)*256 + dir*128 + u;
  const int hstep = dir ? -256 : 256;

  for (int i = 0; i < TT/8; ++i){
    // chunk rotation: waits target loads issued 8 steps (~4000 cy) ago
    if (stg){
      curR = nextR;
      nextR = dir ? rev8(infl) : infl;
      int ci = i + 2; if (ci > TT/8 - 1) ci = TT/8 - 1;
      int t0 = dir ? (TT - 8 - 8*ci) : 8*ci;
      infl = *(const uint4*)(xrow + t0);
    }
    #pragma unroll
    for (int p = 0; p < 8; ++p){
      const int cur = p & 1, nxt = cur ^ 1;

      bf16x8 Af[5];
      const ushort_t* ar = &Abuf[cur][m][0];
      #pragma unroll
      for (int kt=0; kt<5; kt++) Af[kt] = *(const bf16x8*)(ar + kt*32 + q*8);

      floatx4 a[4];
      #pragma unroll
      for (int g=0; g<4; g++)
        a[g] = __builtin_amdgcn_mfma_f32_16x16x32_bf16(Af[0], Bf[g][0], z4, 0,0,0);
      #pragma unroll
      for (int kt=1; kt<5; kt++)
        #pragma unroll
        for (int g=0; g<4; g++)
          a[g] = __builtin_amdgcn_mfma_f32_16x16x32_bf16(Af[kt], Bf[g][kt], a[g], 0,0,0);

      {  // one gate-set per lane: unit u, chain q
        float ig = fsig (a[0][0] + bz[0]);
        float fg = fsig (a[1][0] + bz[1]);
        float gg = ftanh(a[2][0] + bz[2]);
        float og = fsig (a[3][0] + bz[3]);
        float cc = fg*cst + ig*gg;
        cst = cc;
        ushort_t hv = f2bf(og*ftanh(cc));
        Abuf[nxt][q*4][u] = hv;
        *hp = hv; hp += hstep;              // fire-and-forget
      }
      if (stg){
        ushort_t xp = (p < 7) ? elem8(curR, p+1) : elem8(nextR, 0);
        Abuf[nxt][ch*4][128+cx] = xp;
      }
      ldsbar();
    }
  }
}

// ---------------- K2: xz1R[dir][b][t][u(64)][g(4)] = bf16( h0seq[bt][:256] @ Wx1[dir] )
__global__ __launch_bounds__(512) void k_xz1_gemm(const ushort_t* __restrict__ h0seq,
                                                  const ushort_t* __restrict__ WxT,
                                                  ushort_t* __restrict__ xz1)
{
  const int mb  = blockIdx.x;
  const int dir = blockIdx.y;
  const ushort_t* W   = WxT + (size_t)dir*256*256;
  ushort_t*       out = xz1 + (size_t)dir*BB*TT*256;
  const int wave = threadIdx.x >> 6;
  const int lane = threadIdx.x & 63;
  const int mw = wave & 3;
  const int nw = wave >> 2;       // n-half: gates {2nw, 2nw+1}
  const int m_ = lane & 15;
  const int q_ = lane >> 4;

  floatx4 acc[2][8];
  #pragma unroll
  for (int a=0;a<2;a++)
    #pragma unroll
    for (int n=0;n<8;n++) acc[a][n] = (floatx4)0.f;

  const size_t Abase = ((size_t)mb*128 + mw*32 + m_)*256 + q_*8;
  const size_t Bbase = ((size_t)nw*128 + m_)*256 + q_*8;

  for (int kc = 0; kc < 256; kc += 32){
    bf16x8 afr[2];
    #pragma unroll
    for (int mt=0;mt<2;mt++)
      afr[mt] = *(const bf16x8*)(h0seq + Abase + (size_t)mt*16*256 + kc);
    #pragma unroll
    for (int nt=0;nt<8;nt++){
      bf16x8 bfr = *(const bf16x8*)(W + Bbase + (size_t)nt*16*256 + kc);
      #pragma unroll
      for (int mt=0;mt<2;mt++)
        acc[mt][nt] = __builtin_amdgcn_mfma_f32_16x16x32_bf16(afr[mt], bfr, acc[mt][nt], 0,0,0);
    }
  }
  #pragma unroll
  for (int mt=0;mt<2;mt++)
    #pragma unroll
    for (int r=0;r<4;r++){
      size_t bt = (size_t)mb*128 + mw*32 + mt*16 + q_*4 + r;
      ushort_t* rowp = out + bt*256;
      #pragma unroll
      for (int wvz=0; wvz<4; wvz++){
        uint32_t lo = f2bf(acc[mt][wvz][r]);
        uint32_t hi = f2bf(acc[mt][wvz+4][r]);
        *(uint32_t*)(rowp + (wvz*16+m_)*4 + 2*nw) = lo | (hi << 16);
      }
    }
}

// ---------------- K3: layer-1 MFMA scan. 4 chains/WG, 4 waves, 32 WGs. Unrolled x4;
// per-lane xz stream prefetched 4 steps ahead.
__global__ __launch_bounds__(256, 1) void k_lstm1m(
  const ushort_t* __restrict__ xz1R,                // [dir][b][t][u][g] bf16
  const ushort_t* __restrict__ B1T,                 // [dir][n=256][k=64] bf16
  const float* __restrict__ bF, const float* __restrict__ bB,
  float* __restrict__ h1last)                       // [B][128]: fwd 0..63, bwd 64..127
{
  const int dir = blockIdx.x & 1, cb = blockIdx.x >> 1;   // cb 0..15
  const int tid = threadIdx.x;
  const int wv = tid >> 6, lane = tid & 63, m = lane & 15, q = lane >> 4;
  const int u = wv*16 + m;                                // unit 0..63
  const float* bi = dir ? bB : bF;

  __shared__ __align__(16) ushort_t Hbuf[2][16][88];

  bf16x8 Bf[4][2];                        // gate g -> n-tile g*4+wv
  const ushort_t* Bb = B1T + (size_t)dir*256*64;
  #pragma unroll
  for (int g=0; g<4; g++){
    int nt = g*4 + wv;
    #pragma unroll
    for (int kt=0; kt<2; kt++)
      Bf[g][kt] = *(const bf16x8*)(Bb + (size_t)(nt*16+m)*64 + kt*32 + q*8);
  }
  float bz[4];
  #pragma unroll
  for (int g=0; g<4; g++) bz[g] = bi[g*64 + u];

  for (int i = tid; i < (int)(sizeof(Hbuf)/4); i += 256) ((uint32_t*)Hbuf)[i] = 0u;

  const ushort_t* xzr = xz1R + ((size_t)dir*BB + (size_t)(cb*4+q))*TT*256 + (size_t)u*4;
  uint2 pz[4];
  #pragma unroll
  for (int j=0; j<4; j++){
    int tj = dir ? (TT-1-j) : j;
    pz[j] = *(const uint2*)(xzr + (size_t)tj*256);
  }
  __syncthreads();

  const floatx4 z4 = {0.f,0.f,0.f,0.f};
  float cst = 0.f, hl = 0.f;

  for (int i = 0; i < TT/4; ++i){
    #pragma unroll
    for (int p = 0; p < 4; ++p){
      const int s = i*4 + p;
      const int cur = p & 1, nxt = cur ^ 1;

      bf16x8 Af[2];
      const ushort_t* ar = &Hbuf[cur][m][0];
      Af[0] = *(const bf16x8*)(ar + q*8);
      Af[1] = *(const bf16x8*)(ar + 32 + q*8);

      floatx4 a0 = __builtin_amdgcn_mfma_f32_16x16x32_bf16(Af[0], Bf[0][0], z4, 0,0,0);
      floatx4 a1 = __builtin_amdgcn_mfma_f32_16x16x32_bf16(Af[0], Bf[1][0], z4, 0,0,0);
      floatx4 a2 = __builtin_amdgcn_mfma_f32_16x16x32_bf16(Af[0], Bf[2][0], z4, 0,0,0);
      floatx4 a3 = __builtin_amdgcn_mfma_f32_16x16x32_bf16(Af[0], Bf[3][0], z4, 0,0,0);
      a0 = __builtin_amdgcn_mfma_f32_16x16x32_bf16(Af[1], Bf[0][1], a0, 0,0,0);
      a1 = __builtin_amdgcn_mfma_f32_16x16x32_bf16(Af[1], Bf[1][1], a1, 0,0,0);
      a2 = __builtin_amdgcn_mfma_f32_16x16x32_bf16(Af[1], Bf[2][1], a2, 0,0,0);
      a3 = __builtin_amdgcn_mfma_f32_16x16x32_bf16(Af[1], Bf[3][1], a3, 0,0,0);

      // consume pz[p] (loaded 4 steps ago), then reload for step s+4
      float z0 = a0[0] + bz[0] + bf2f((ushort_t)(pz[p].x & 0xffff));
      float z1 = a1[0] + bz[1] + bf2f((ushort_t)(pz[p].x >> 16));
      float z2 = a2[0] + bz[2] + bf2f((ushort_t)(pz[p].y & 0xffff));
      float z3 = a3[0] + bz[3] + bf2f((ushort_t)(pz[p].y >> 16));
      {
        int sn = s + 4; if (sn > TT-1) sn = TT-1;
        int tn = dir ? (TT-1-sn) : sn;
        pz[p] = *(const uint2*)(xzr + (size_t)tn*256);
      }

      {
        float ig = fsig(z0), fg = fsig(z1), og = fsig(z3);
        float gg = ftanh(z2);
        float cc = fg*cst + ig*gg;
        cst = cc;
        hl = og*ftanh(cc);
        Hbuf[nxt][q*4][u] = f2bf(hl);
      }
      ldsbar();
    }
  }
  h1last[(size_t)(cb*4 + q)*128 + dir*64 + u] = hl;
}

// ---------------- K4: dense head
__global__ __launch_bounds__(128) void k_head(
  const float* __restrict__ h1last,
  const float* __restrict__ d0W, const float* __restrict__ d0b,
  const float* __restrict__ d1W, const float* __restrict__ d1b,
  const float* __restrict__ oW,  const float* __restrict__ ob,
  float* __restrict__ outp)
{
  const int b = blockIdx.x;
  const int j = threadIdx.x;
  __shared__ float v0[128], v1[128];
  v0[j] = h1last[b*128 + j];
  __syncthreads();
  float acc = d0b[j];
  #pragma unroll
  for (int k=0;k<128;k++) acc += v0[k]*d0W[k*128 + j];
  v1[j] = fmaxf(acc, 0.f);
  __syncthreads();
  if (j < 64){
    float a2 = d1b[j];
    #pragma unroll
    for (int k=0;k<128;k++) a2 += v1[k]*d1W[k*64 + j];
    float p = fmaxf(a2, 0.f) * oW[j];
    #pragma unroll
    for (int off=32; off>0; off>>=1) p += __shfl_down(p, off, 64);
    if (j == 0) outp[b] = 1.f/(1.f + __expf(-(p + ob[0])));
  }
}

extern "C" void kernel_launch(void* const* d_in, const int* in_sizes, int n_in,
                              void* d_out, int out_size, void* d_ws, size_t ws_size,
                              hipStream_t stream)
{
  const float* x     = (const float*)d_in[0];
  const float* l0fWx = (const float*)d_in[1];
  const float* l0fWh = (const float*)d_in[2];
  const float* l0fb  = (const float*)d_in[3];
  const float* l0bWx = (const float*)d_in[4];
  const float* l0bWh = (const float*)d_in[5];
  const float* l0bb  = (const float*)d_in[6];
  const float* l1fWx = (const float*)d_in[7];
  const float* l1fWh = (const float*)d_in[8];
  const float* l1fb  = (const float*)d_in[9];
  const float* l1bWx = (const float*)d_in[10];
  const float* l1bWh = (const float*)d_in[11];
  const float* l1bb  = (const float*)d_in[12];
  const float* d0W = (const float*)d_in[13];
  const float* d0b = (const float*)d_in[14];
  const float* d1W = (const float*)d_in[15];
  const float* d1b = (const float*)d_in[16];
  const float* oW  = (const float*)d_in[17];
  const float* ob  = (const float*)d_in[18];
  float* outp = (float*)d_out;

  char* ws = (char*)d_ws;
  const size_t OFF_XT  = 0;                        // xc: 7,208,960 (slot 7,864,320)
  const size_t OFF_H0  = OFF_XT  + 7864320ull;     // 83,886,080
  const size_t OFF_XZ  = OFF_H0  + 83886080ull;    // 167,772,160 (xz1R)
  const size_t OFF_WT  = OFF_XZ  + 167772160ull;   // 262,144
  const size_t OFF_B0  = OFF_WT  + 262144ull;      // 327,680
  const size_t OFF_B1  = OFF_B0  + 327680ull;      // 65,536
  const size_t OFF_H1  = OFF_B1  + 65536ull;       // 32,768

  ushort_t* xc  = (ushort_t*)(ws + OFF_XT);
  ushort_t* h0  = (ushort_t*)(ws + OFF_H0);
  ushort_t* xz1 = (ushort_t*)(ws + OFF_XZ);
  ushort_t* WT  = (ushort_t*)(ws + OFF_WT);
  ushort_t* B0T = (ushort_t*)(ws + OFF_B0);
  ushort_t* B1T = (ushort_t*)(ws + OFF_B1);
  float*    h1l = (float*)(ws + OFF_H1);

  hipLaunchKernelGGL(k_convert_x,   dim3(3520), dim3(256), 0, stream, x, xc);
  hipLaunchKernelGGL(k_prep_l0,     dim3(640),  dim3(256), 0, stream, l0fWx, l0fWh, l0bWx, l0bWh, B0T);
  hipLaunchKernelGGL(k_prep_l1,     dim3(128),  dim3(256), 0, stream, l1fWh, l1bWh, B1T);
  hipLaunchKernelGGL(k_prep_wxT,    dim3(512),  dim3(256), 0, stream, l1fWx, l1bWx, WT);
  hipLaunchKernelGGL(k_lstm0m,      dim3(32),   dim3(512), 0, stream, xc, B0T, l0fb, l0bb, h0);
  hipLaunchKernelGGL(k_xz1_gemm,    dim3(1280,2), dim3(512), 0, stream, h0, WT, xz1);
  hipLaunchKernelGGL(k_lstm1m,      dim3(32),   dim3(256), 0, stream, xz1, B1T, l1fb, l1bb, h1l);
  hipLaunchKernelGGL(k_head,        dim3(64),   dim3(128), 0, stream,
                     h1l, d0W, d0b, d1W, d1b, oW, ob, outp);
}